// Round 1
// baseline (6086.403 us; speedup 1.0000x reference)
//
#include <hip/hip_runtime.h>
#include <cstdint>

#define DIM 128
#define DSTATE 256
#define NB 64
#define NT 4096
#define REPS 1e-5f

typedef float4 f4;

__device__ __forceinline__ void fma4(f4& a, float s, const f4& w) {
  a.x = fmaf(s, w.x, a.x);
  a.y = fmaf(s, w.y, a.y);
  a.z = fmaf(s, w.z, a.z);
  a.w = fmaf(s, w.w, a.w);
}

// ---------------- precompute: fused weight matrices ----------------
// WdO[c,j] = sum_k Wout[c,k] * Wd[k,j]
__global__ void k_wdo(const float* __restrict__ Wout, const float* __restrict__ Wd,
                      float* __restrict__ WdO) {
  int c = blockIdx.x, j = threadIdx.x;
  float s = 0.f;
  for (int k = 0; k < 128; ++k) s = fmaf(Wout[c * 128 + k], Wd[k * 128 + j], s);
  WdO[c * 128 + j] = s;
}

// WuT[k][c] = sum_j Wab[c, 256+j] * Win[j, k]   (layout [128][256])
__global__ void k_wut(const float* __restrict__ Wab, const float* __restrict__ Win,
                      float* __restrict__ WuT) {
  int c = blockIdx.x;   // 256
  int k = threadIdx.x;  // 128
  float s = 0.f;
  for (int j = 0; j < 128; ++j) s = fmaf(Wab[c * 384 + 256 + j], Win[j * 128 + k], s);
  WuT[k * 256 + c] = s;
}

// WallT rows 128..383: WcOT[k][c] = sum_j Wout[c,j] * Wc[j,k]
__global__ void k_wcot(const float* __restrict__ Wout, const float* __restrict__ Wc,
                       float* __restrict__ WallT) {
  int c = blockIdx.x;   // 128
  int k = threadIdx.x;  // 256
  float s = 0.f;
  for (int j = 0; j < 128; ++j) s = fmaf(Wout[c * 128 + j], Wc[j * 256 + k], s);
  WallT[(size_t)(128 + k) * 128 + c] = s;
}

// WallT rows 0..127: WxT[k][c] = sum_j WdO[c,j] * Win[j,k]
__global__ void k_wxt(const float* __restrict__ WdO, const float* __restrict__ Win,
                      float* __restrict__ WallT) {
  int c = blockIdx.x;   // 128
  int k = threadIdx.x;  // 128
  float s = 0.f;
  for (int j = 0; j < 128; ++j) s = fmaf(WdO[c * 128 + j], Win[j * 128 + k], s);
  WallT[(size_t)k * 128 + c] = s;
}

// fused biases
__global__ void k_bias(const float* __restrict__ Wout, const float* __restrict__ WdO,
                       const float* __restrict__ Wab, const float* __restrict__ bin,
                       const float* __restrict__ bab, const float* __restrict__ bc,
                       const float* __restrict__ bd, const float* __restrict__ bout,
                       float* __restrict__ bu, float* __restrict__ ball) {
  int t = threadIdx.x;  // 256
  if (t < 128) {
    float s = bout[t];
    for (int j = 0; j < 128; ++j) {
      s = fmaf(Wout[t * 128 + j], bc[j] + bd[j], s);
      s = fmaf(WdO[t * 128 + j], bin[j], s);
    }
    ball[t] = s;
  }
  float s2 = bab[t];
  for (int j = 0; j < 128; ++j) s2 = fmaf(Wab[t * 384 + 256 + j], bin[j], s2);
  bu[t] = s2;
}

// ---------------- u = x @ WuT + bu  ([B*T,128]@[128,256]) ----------------
// tile 128 rows x 128 cols, per-thread 8x8, K chunks of 32
__global__ __launch_bounds__(256, 2) void k_ugemm(const float* __restrict__ x,
                                                  const float* __restrict__ WuT,
                                                  const float* __restrict__ bu,
                                                  float* __restrict__ u) {
  __shared__ f4 xs[128 * 9];   // [row][36 floats] padded
  __shared__ f4 ws[32 * 32];   // [k][128 floats]
  const int tid = threadIdx.x;
  const int tc = tid & 15;
  const int trr = tid >> 4;
  const size_t row0 = (size_t)blockIdx.x * 128;
  const int cb = blockIdx.y * 128;

  f4 accA[8], accB[8];
  {
    f4 ba = *(const f4*)(bu + cb + tc * 4);
    f4 bb = *(const f4*)(bu + cb + 64 + tc * 4);
#pragma unroll
    for (int i = 0; i < 8; ++i) { accA[i] = ba; accB[i] = bb; }
  }

  for (int k0 = 0; k0 < DIM; k0 += 32) {
#pragma unroll
    for (int l = 0; l < 4; ++l) {
      int f = tid + l * 256;
      int rr = f >> 3, kq = f & 7;
      xs[rr * 9 + kq] = *(const f4*)(x + (row0 + rr) * DIM + k0 + kq * 4);
    }
#pragma unroll
    for (int l = 0; l < 4; ++l) {
      int f = tid + l * 256;
      int kk = f >> 5, cq = f & 31;
      ws[kk * 32 + cq] = *(const f4*)(WuT + (size_t)(k0 + kk) * DSTATE + cb + cq * 4);
    }
    __syncthreads();
#pragma unroll
    for (int g = 0; g < 8; ++g) {
      f4 xv[8];
#pragma unroll
      for (int i = 0; i < 8; ++i) xv[i] = xs[(trr + 16 * i) * 9 + g];
#pragma unroll
      for (int d = 0; d < 4; ++d) {
        f4 wa = ws[(g * 4 + d) * 32 + tc];
        f4 wb = ws[(g * 4 + d) * 32 + 16 + tc];
#pragma unroll
        for (int i = 0; i < 8; ++i) {
          float xm = (d == 0) ? xv[i].x : (d == 1) ? xv[i].y : (d == 2) ? xv[i].z : xv[i].w;
          fma4(accA[i], xm, wa);
          fma4(accB[i], xm, wb);
        }
      }
    }
    __syncthreads();
  }
#pragma unroll
  for (int i = 0; i < 8; ++i) {
    size_t r = row0 + trr + 16 * i;
    *(f4*)(u + r * DSTATE + cb + tc * 4) = accA[i];
    *(f4*)(u + r * DSTATE + cb + 64 + tc * 4) = accB[i];
  }
}

// ---------------- sequential scan: 1 WG per batch ----------------
// thread pair (r, half): dot(W_a[r, half*128 .. +128), lat[half*128..]) from VGPR weights
// h overwrites u in place.
__global__ __launch_bounds__(512, 2) void k_scan(const float* __restrict__ Wab,
                                                 const float* __restrict__ wlng,
                                                 float* u) {
  __shared__ float lat[DSTATE];
  __shared__ float part[8];
  const int tid = threadIdx.x;
  const int r = tid >> 1;
  const int half = tid & 1;
  const int lane = tid & 63;
  const int wv = tid >> 6;
  float* ub = u + (size_t)blockIdx.x * ((size_t)NT * DSTATE);

  f4 w[32];
  {
    const f4* wrow = (const f4*)(Wab + r * 384 + half * 128);
#pragma unroll
    for (int q = 0; q < 32; ++q) w[q] = wrow[q];
  }
  const float wln = wlng[r];
  if (tid < DSTATE) lat[tid] = 0.f;
  __syncthreads();

  const f4* lat4 = ((const f4*)lat) + half * 32;

  float uA = ub[r];
  float uB = ub[DSTATE + r];

  for (int t = 0; t < NT; t += 2) {
    float pfA = 0.f, pfB = 0.f;
    if (t + 2 < NT) {
      pfA = ub[(size_t)(t + 2) * DSTATE + r];
      pfB = ub[(size_t)(t + 3) * DSTATE + r];
    }
#define SCAN_STEP(UVAL, TT_)                                                  \
    {                                                                         \
      float a0 = 0.f, a1 = 0.f, a2 = 0.f, a3 = 0.f;                           \
      _Pragma("unroll")                                                       \
      for (int q = 0; q < 32; ++q) {                                          \
        f4 lv = lat4[q];                                                      \
        a0 = fmaf(w[q].x, lv.x, a0);                                          \
        a1 = fmaf(w[q].y, lv.y, a1);                                          \
        a2 = fmaf(w[q].z, lv.z, a2);                                          \
        a3 = fmaf(w[q].w, lv.w, a3);                                          \
      }                                                                       \
      float dot = (a0 + a1) + (a2 + a3);                                      \
      dot += __shfl_xor(dot, 1);                                              \
      float pre = dot + (UVAL);                                               \
      float s = pre * pre;                                                    \
      s += __shfl_xor(s, 2);  s += __shfl_xor(s, 4);                          \
      s += __shfl_xor(s, 8);  s += __shfl_xor(s, 16);                         \
      s += __shfl_xor(s, 32);                                                 \
      if (lane == 0) part[wv] = s;                                            \
      __syncthreads();                                                        \
      float tot = ((part[0] + part[1]) + (part[2] + part[3])) +               \
                  ((part[4] + part[5]) + (part[6] + part[7]));                \
      float scale = rsqrtf(tot * (1.0f / 256.0f) + REPS);                     \
      float ln = pre * scale * wln;                                           \
      if (!half) {                                                            \
        lat[r] = ln;                                                          \
        ub[(size_t)(TT_) * DSTATE + r] = ln;                                  \
      }                                                                       \
      __syncthreads();                                                        \
    }
    SCAN_STEP(uA, t)
    SCAN_STEP(uB, t + 1)
#undef SCAN_STEP
    uA = pfA;
    uB = pfB;
  }
}

// ---------------- out = [x,h] @ WallT + ball  ([B*T,384]@[384,128]) ----------------
__global__ __launch_bounds__(256, 2) void k_ogemm(const float* __restrict__ x,
                                                  const float* __restrict__ h,
                                                  const float* __restrict__ WallT,
                                                  const float* __restrict__ ball,
                                                  float* __restrict__ out) {
  __shared__ f4 xs[128 * 9];
  __shared__ f4 ws[32 * 32];
  const int tid = threadIdx.x;
  const int tc = tid & 15;
  const int trr = tid >> 4;
  const size_t row0 = (size_t)blockIdx.x * 128;

  f4 accA[8], accB[8];
  {
    f4 ba = *(const f4*)(ball + tc * 4);
    f4 bb = *(const f4*)(ball + 64 + tc * 4);
#pragma unroll
    for (int i = 0; i < 8; ++i) { accA[i] = ba; accB[i] = bb; }
  }

  for (int ch = 0; ch < 12; ++ch) {
    const int k0 = ch * 32;
    const float* src = (k0 < DIM) ? x : h;
    const int rstride = (k0 < DIM) ? DIM : DSTATE;
    const int koff = (k0 < DIM) ? k0 : (k0 - DIM);
#pragma unroll
    for (int l = 0; l < 4; ++l) {
      int f = tid + l * 256;
      int rr = f >> 3, kq = f & 7;
      xs[rr * 9 + kq] = *(const f4*)(src + (row0 + rr) * rstride + koff + kq * 4);
    }
#pragma unroll
    for (int l = 0; l < 4; ++l) {
      int f = tid + l * 256;
      int kk = f >> 5, cq = f & 31;
      ws[kk * 32 + cq] = *(const f4*)(WallT + (size_t)(k0 + kk) * DIM + cq * 4);
    }
    __syncthreads();
#pragma unroll
    for (int g = 0; g < 8; ++g) {
      f4 xv[8];
#pragma unroll
      for (int i = 0; i < 8; ++i) xv[i] = xs[(trr + 16 * i) * 9 + g];
#pragma unroll
      for (int d = 0; d < 4; ++d) {
        f4 wa = ws[(g * 4 + d) * 32 + tc];
        f4 wb = ws[(g * 4 + d) * 32 + 16 + tc];
#pragma unroll
        for (int i = 0; i < 8; ++i) {
          float xm = (d == 0) ? xv[i].x : (d == 1) ? xv[i].y : (d == 2) ? xv[i].z : xv[i].w;
          fma4(accA[i], xm, wa);
          fma4(accB[i], xm, wb);
        }
      }
    }
    __syncthreads();
  }
#pragma unroll
  for (int i = 0; i < 8; ++i) {
    size_t r = row0 + trr + 16 * i;
    *(f4*)(out + r * DIM + tc * 4) = accA[i];
    *(f4*)(out + r * DIM + 64 + tc * 4) = accB[i];
  }
}

extern "C" void kernel_launch(void* const* d_in, const int* in_sizes, int n_in,
                              void* d_out, int out_size, void* d_ws, size_t ws_size,
                              hipStream_t stream) {
  const float* x    = (const float*)d_in[0];
  const float* Win  = (const float*)d_in[1];
  const float* bin  = (const float*)d_in[2];
  const float* Wab  = (const float*)d_in[3];
  const float* bab  = (const float*)d_in[4];
  const float* wln  = (const float*)d_in[5];
  const float* Wc   = (const float*)d_in[6];
  const float* bc   = (const float*)d_in[7];
  const float* Wd   = (const float*)d_in[8];
  const float* bd   = (const float*)d_in[9];
  const float* Wout = (const float*)d_in[10];
  const float* bout = (const float*)d_in[11];
  float* out = (float*)d_out;
  float* wsf = (float*)d_ws;

  float* u     = wsf;                                   // 64*4096*256 floats (u -> h in place)
  float* WuT   = u + (size_t)NB * NT * DSTATE;          // 128*256
  float* WallT = WuT + (size_t)DIM * DSTATE;            // 384*128
  float* WdO   = WallT + (size_t)384 * DIM;             // 128*128
  float* bu    = WdO + (size_t)DIM * DIM;               // 256
  float* ball  = bu + DSTATE;                           // 128

  hipLaunchKernelGGL(k_wdo, dim3(128), dim3(128), 0, stream, Wout, Wd, WdO);
  hipLaunchKernelGGL(k_wut, dim3(256), dim3(128), 0, stream, Wab, Win, WuT);
  hipLaunchKernelGGL(k_wcot, dim3(128), dim3(256), 0, stream, Wout, Wc, WallT);
  hipLaunchKernelGGL(k_wxt, dim3(128), dim3(128), 0, stream, WdO, Win, WallT);
  hipLaunchKernelGGL(k_bias, dim3(1), dim3(256), 0, stream,
                     Wout, WdO, Wab, bin, bab, bc, bd, bout, bu, ball);
  hipLaunchKernelGGL(k_ugemm, dim3(2048, 2), dim3(256), 0, stream, x, WuT, bu, u);
  hipLaunchKernelGGL(k_scan, dim3(NB), dim3(512), 0, stream, Wab, wln, u);
  hipLaunchKernelGGL(k_ogemm, dim3(2048), dim3(256), 0, stream, x, u, WallT, ball, out);
}

// Round 2
// 4249.553 us; speedup vs baseline: 1.4322x; 1.4322x over previous
//
#include <hip/hip_runtime.h>
#include <cstdint>

#define DIM 128
#define DSTATE 256
#define NB 64
#define NT 4096
#define REPS 1e-5f

typedef float4 f4;

__device__ __forceinline__ void fma4(f4& a, float s, const f4& w) {
  a.x = fmaf(s, w.x, a.x);
  a.y = fmaf(s, w.y, a.y);
  a.z = fmaf(s, w.z, a.z);
  a.w = fmaf(s, w.w, a.w);
}

// elementwise a += b*c
__device__ __forceinline__ void fma44(f4& a, const f4& b, const f4& c) {
  a.x = fmaf(b.x, c.x, a.x);
  a.y = fmaf(b.y, c.y, a.y);
  a.z = fmaf(b.z, c.z, a.z);
  a.w = fmaf(b.w, c.w, a.w);
}

// ---------------- precompute: fused weight matrices ----------------
// WdO[c,j] = sum_k Wout[c,k] * Wd[k,j]
__global__ void k_wdo(const float* __restrict__ Wout, const float* __restrict__ Wd,
                      float* __restrict__ WdO) {
  int c = blockIdx.x, j = threadIdx.x;
  float s = 0.f;
  for (int k = 0; k < 128; ++k) s = fmaf(Wout[c * 128 + k], Wd[k * 128 + j], s);
  WdO[c * 128 + j] = s;
}

// WuT[k][c] = sum_j Wab[c, 256+j] * Win[j, k]   (layout [128][256])
__global__ void k_wut(const float* __restrict__ Wab, const float* __restrict__ Win,
                      float* __restrict__ WuT) {
  int c = blockIdx.x;   // 256
  int k = threadIdx.x;  // 128
  float s = 0.f;
  for (int j = 0; j < 128; ++j) s = fmaf(Wab[c * 384 + 256 + j], Win[j * 128 + k], s);
  WuT[k * 256 + c] = s;
}

// WallT rows 128..383: WcOT[k][c] = sum_j Wout[c,j] * Wc[j,k]
__global__ void k_wcot(const float* __restrict__ Wout, const float* __restrict__ Wc,
                       float* __restrict__ WallT) {
  int c = blockIdx.x;   // 128
  int k = threadIdx.x;  // 256
  float s = 0.f;
  for (int j = 0; j < 128; ++j) s = fmaf(Wout[c * 128 + j], Wc[j * 256 + k], s);
  WallT[(size_t)(128 + k) * 128 + c] = s;
}

// WallT rows 0..127: WxT[k][c] = sum_j WdO[c,j] * Win[j,k]
__global__ void k_wxt(const float* __restrict__ WdO, const float* __restrict__ Win,
                      float* __restrict__ WallT) {
  int c = blockIdx.x;   // 128
  int k = threadIdx.x;  // 128
  float s = 0.f;
  for (int j = 0; j < 128; ++j) s = fmaf(WdO[c * 128 + j], Win[j * 128 + k], s);
  WallT[(size_t)k * 128 + c] = s;
}

// Wf[r][k] = Wab[r][k] * wln[k]   (rmsnorm weight folded into recurrence matrix)
__global__ void k_wfold(const float* __restrict__ Wab, const float* __restrict__ wln,
                        float* __restrict__ Wf) {
  int r = blockIdx.x;   // 256
  int k = threadIdx.x;  // 256
  Wf[r * 256 + k] = Wab[r * 384 + k] * wln[k];
}

// fused biases
__global__ void k_bias(const float* __restrict__ Wout, const float* __restrict__ WdO,
                       const float* __restrict__ Wab, const float* __restrict__ bin,
                       const float* __restrict__ bab, const float* __restrict__ bc,
                       const float* __restrict__ bd, const float* __restrict__ bout,
                       float* __restrict__ bu, float* __restrict__ ball) {
  int t = threadIdx.x;  // 256
  if (t < 128) {
    float s = bout[t];
    for (int j = 0; j < 128; ++j) {
      s = fmaf(Wout[t * 128 + j], bc[j] + bd[j], s);
      s = fmaf(WdO[t * 128 + j], bin[j], s);
    }
    ball[t] = s;
  }
  float s2 = bab[t];
  for (int j = 0; j < 128; ++j) s2 = fmaf(Wab[t * 384 + 256 + j], bin[j], s2);
  bu[t] = s2;
}

// ---------------- u = x @ WuT + bu  ([B*T,128]@[128,256]) ----------------
__global__ __launch_bounds__(256, 2) void k_ugemm(const float* __restrict__ x,
                                                  const float* __restrict__ WuT,
                                                  const float* __restrict__ bu,
                                                  float* __restrict__ u) {
  __shared__ f4 xs[128 * 9];   // [row][36 floats] padded
  __shared__ f4 ws[32 * 32];   // [k][128 floats]
  const int tid = threadIdx.x;
  const int tc = tid & 15;
  const int trr = tid >> 4;
  const size_t row0 = (size_t)blockIdx.x * 128;
  const int cb = blockIdx.y * 128;

  f4 accA[8], accB[8];
  {
    f4 ba = *(const f4*)(bu + cb + tc * 4);
    f4 bb = *(const f4*)(bu + cb + 64 + tc * 4);
#pragma unroll
    for (int i = 0; i < 8; ++i) { accA[i] = ba; accB[i] = bb; }
  }

  for (int k0 = 0; k0 < DIM; k0 += 32) {
#pragma unroll
    for (int l = 0; l < 4; ++l) {
      int f = tid + l * 256;
      int rr = f >> 3, kq = f & 7;
      xs[rr * 9 + kq] = *(const f4*)(x + (row0 + rr) * DIM + k0 + kq * 4);
    }
#pragma unroll
    for (int l = 0; l < 4; ++l) {
      int f = tid + l * 256;
      int kk = f >> 5, cq = f & 31;
      ws[kk * 32 + cq] = *(const f4*)(WuT + (size_t)(k0 + kk) * DSTATE + cb + cq * 4);
    }
    __syncthreads();
#pragma unroll
    for (int g = 0; g < 8; ++g) {
      f4 xv[8];
#pragma unroll
      for (int i = 0; i < 8; ++i) xv[i] = xs[(trr + 16 * i) * 9 + g];
#pragma unroll
      for (int d = 0; d < 4; ++d) {
        f4 wa = ws[(g * 4 + d) * 32 + tc];
        f4 wb = ws[(g * 4 + d) * 32 + 16 + tc];
#pragma unroll
        for (int i = 0; i < 8; ++i) {
          float xm = (d == 0) ? xv[i].x : (d == 1) ? xv[i].y : (d == 2) ? xv[i].z : xv[i].w;
          fma4(accA[i], xm, wa);
          fma4(accB[i], xm, wb);
        }
      }
    }
    __syncthreads();
  }
#pragma unroll
  for (int i = 0; i < 8; ++i) {
    size_t r = row0 + trr + 16 * i;
    *(f4*)(u + r * DSTATE + cb + tc * 4) = accA[i];
    *(f4*)(u + r * DSTATE + cb + 64 + tc * 4) = accB[i];
  }
}

// ---------------- sequential scan: 1 WG (512 thr) per batch ----------------
// Decomposition: lane = rb*4+kb (rb 0..15, kb 0..3); wave w owns rows w*32+rb*2+{0,1}.
// Thread: 2 rows x 64-float k-slice (kb*64..) => 16 ds_read_b128 from padded LDS
// (slice base stride 68 floats -> banks 4*kb+4q+e, conflict-free, immediate offsets).
// One barrier/step: store UNNORMALIZED pre-activation; rmsnorm scale s is applied to
// next step's dot (W' = Wa*diag(wln) precomputed, so W'.(pre)*s == Wa.(h_prev)).
__global__ __launch_bounds__(512, 2) void k_scan(const float* __restrict__ Wf,
                                                 const float* __restrict__ wlng,
                                                 float* __restrict__ u) {
  __shared__ float lat[2][4 * 68];   // 4 slices x (64 data + 4 pad)
  __shared__ float part[2][8];
  const int tid = threadIdx.x;
  const int w = tid >> 6;
  const int lane = tid & 63;
  const int rb = lane >> 2;
  const int kb = lane & 3;
  const int r0 = w * 32 + rb * 2;
  float* ub = u + (size_t)blockIdx.x * ((size_t)NT * DSTATE);

  // W' rows (wln folded) in registers: 2 rows x 64 floats = 32 f4
  f4 W0[16], W1[16];
  {
    const f4* pw0 = (const f4*)(Wf + (size_t)r0 * 256 + kb * 64);
    const f4* pw1 = (const f4*)(Wf + (size_t)(r0 + 1) * 256 + kb * 64);
#pragma unroll
    for (int q = 0; q < 16; ++q) { W0[q] = pw0[q]; W1[q] = pw1[q]; }
  }
  const float wln0 = wlng[r0], wln1 = wlng[r0 + 1];

  if (tid < 256) lat[0][(tid >> 6) * 68 + (tid & 63)] = 0.f;
  __syncthreads();

  const f4* rd0 = (const f4*)(lat[0] + kb * 68);
  const f4* rd1 = (const f4*)(lat[1] + kb * 68);
  const int wri = (r0 >> 6) * 68 + (r0 & 63);   // padded position of row r0
  float* wr0 = lat[0] + wri;
  float* wr1 = lat[1] + wri;

  float sprev = 1.0f;
  float u0A = ub[r0], u1A = ub[r0 + 1];
  float u0B = ub[DSTATE + r0], u1B = ub[DSTATE + r0 + 1];

#define SCAN_STEP(RD, WR, PP, U0, U1, TT)                                     \
  {                                                                           \
    f4 a0 = {0.f, 0.f, 0.f, 0.f}, a1 = {0.f, 0.f, 0.f, 0.f};                  \
    _Pragma("unroll")                                                         \
    for (int q = 0; q < 16; ++q) {                                            \
      f4 lv = RD[q];                                                          \
      fma44(a0, W0[q], lv);                                                   \
      fma44(a1, W1[q], lv);                                                   \
    }                                                                         \
    float d0 = (a0.x + a0.y) + (a0.z + a0.w);                                 \
    float d1 = (a1.x + a1.y) + (a1.z + a1.w);                                 \
    d0 += __shfl_xor(d0, 1); d0 += __shfl_xor(d0, 2);                         \
    d1 += __shfl_xor(d1, 1); d1 += __shfl_xor(d1, 2);                         \
    float pre0 = fmaf(d0, sprev, U0);                                         \
    float pre1 = fmaf(d1, sprev, U1);                                         \
    if (kb == 0) *(float2*)(WR) = make_float2(pre0, pre1);                    \
    float ss = fmaf(pre1, pre1, pre0 * pre0);                                 \
    ss += __shfl_xor(ss, 4);  ss += __shfl_xor(ss, 8);                        \
    ss += __shfl_xor(ss, 16); ss += __shfl_xor(ss, 32);                       \
    if (lane == 0) part[PP][w] = ss;                                          \
    __syncthreads();                                                          \
    float tot = ((part[PP][0] + part[PP][1]) + (part[PP][2] + part[PP][3])) + \
                ((part[PP][4] + part[PP][5]) + (part[PP][6] + part[PP][7]));  \
    float s = rsqrtf(tot * (1.0f / 256.0f) + REPS);                           \
    if (kb == 0) {                                                            \
      *(float2*)&ub[(size_t)(TT)*DSTATE + r0] =                               \
          make_float2(pre0 * s * wln0, pre1 * s * wln1);                      \
    }                                                                         \
    sprev = s;                                                                \
  }

  for (int t = 0; t < NT; t += 2) {
    float pf0A = 0.f, pf1A = 0.f, pf0B = 0.f, pf1B = 0.f;
    if (t + 2 < NT) {
      pf0A = ub[(size_t)(t + 2) * DSTATE + r0];
      pf1A = ub[(size_t)(t + 2) * DSTATE + r0 + 1];
      pf0B = ub[(size_t)(t + 3) * DSTATE + r0];
      pf1B = ub[(size_t)(t + 3) * DSTATE + r0 + 1];
    }
    SCAN_STEP(rd0, wr1, 0, u0A, u1A, t)
    SCAN_STEP(rd1, wr0, 1, u0B, u1B, t + 1)
    u0A = pf0A; u1A = pf1A; u0B = pf0B; u1B = pf1B;
  }
#undef SCAN_STEP
}

// ---------------- out = [x,h] @ WallT + ball  ([B*T,384]@[384,128]) ----------------
__global__ __launch_bounds__(256, 2) void k_ogemm(const float* __restrict__ x,
                                                  const float* __restrict__ h,
                                                  const float* __restrict__ WallT,
                                                  const float* __restrict__ ball,
                                                  float* __restrict__ out) {
  __shared__ f4 xs[128 * 9];
  __shared__ f4 ws[32 * 32];
  const int tid = threadIdx.x;
  const int tc = tid & 15;
  const int trr = tid >> 4;
  const size_t row0 = (size_t)blockIdx.x * 128;

  f4 accA[8], accB[8];
  {
    f4 ba = *(const f4*)(ball + tc * 4);
    f4 bb = *(const f4*)(ball + 64 + tc * 4);
#pragma unroll
    for (int i = 0; i < 8; ++i) { accA[i] = ba; accB[i] = bb; }
  }

  for (int ch = 0; ch < 12; ++ch) {
    const int k0 = ch * 32;
    const float* src = (k0 < DIM) ? x : h;
    const int rstride = (k0 < DIM) ? DIM : DSTATE;
    const int koff = (k0 < DIM) ? k0 : (k0 - DIM);
#pragma unroll
    for (int l = 0; l < 4; ++l) {
      int f = tid + l * 256;
      int rr = f >> 3, kq = f & 7;
      xs[rr * 9 + kq] = *(const f4*)(src + (row0 + rr) * rstride + koff + kq * 4);
    }
#pragma unroll
    for (int l = 0; l < 4; ++l) {
      int f = tid + l * 256;
      int kk = f >> 5, cq = f & 31;
      ws[kk * 32 + cq] = *(const f4*)(WallT + (size_t)(k0 + kk) * DIM + cq * 4);
    }
    __syncthreads();
#pragma unroll
    for (int g = 0; g < 8; ++g) {
      f4 xv[8];
#pragma unroll
      for (int i = 0; i < 8; ++i) xv[i] = xs[(trr + 16 * i) * 9 + g];
#pragma unroll
      for (int d = 0; d < 4; ++d) {
        f4 wa = ws[(g * 4 + d) * 32 + tc];
        f4 wb = ws[(g * 4 + d) * 32 + 16 + tc];
#pragma unroll
        for (int i = 0; i < 8; ++i) {
          float xm = (d == 0) ? xv[i].x : (d == 1) ? xv[i].y : (d == 2) ? xv[i].z : xv[i].w;
          fma4(accA[i], xm, wa);
          fma4(accB[i], xm, wb);
        }
      }
    }
    __syncthreads();
  }
#pragma unroll
  for (int i = 0; i < 8; ++i) {
    size_t r = row0 + trr + 16 * i;
    *(f4*)(out + r * DIM + tc * 4) = accA[i];
    *(f4*)(out + r * DIM + 64 + tc * 4) = accB[i];
  }
}

extern "C" void kernel_launch(void* const* d_in, const int* in_sizes, int n_in,
                              void* d_out, int out_size, void* d_ws, size_t ws_size,
                              hipStream_t stream) {
  const float* x    = (const float*)d_in[0];
  const float* Win  = (const float*)d_in[1];
  const float* bin  = (const float*)d_in[2];
  const float* Wab  = (const float*)d_in[3];
  const float* bab  = (const float*)d_in[4];
  const float* wln  = (const float*)d_in[5];
  const float* Wc   = (const float*)d_in[6];
  const float* bc   = (const float*)d_in[7];
  const float* Wd   = (const float*)d_in[8];
  const float* bd   = (const float*)d_in[9];
  const float* Wout = (const float*)d_in[10];
  const float* bout = (const float*)d_in[11];
  float* out = (float*)d_out;
  float* wsf = (float*)d_ws;

  float* u     = wsf;                                   // 64*4096*256 floats (u -> h in place)
  float* WuT   = u + (size_t)NB * NT * DSTATE;          // 128*256
  float* WallT = WuT + (size_t)DIM * DSTATE;            // 384*128
  float* WdO   = WallT + (size_t)384 * DIM;             // 128*128
  float* Wf    = WdO + (size_t)DIM * DIM;               // 256*256
  float* bu    = Wf + (size_t)DSTATE * DSTATE;          // 256
  float* ball  = bu + DSTATE;                           // 128

  hipLaunchKernelGGL(k_wdo, dim3(128), dim3(128), 0, stream, Wout, Wd, WdO);
  hipLaunchKernelGGL(k_wut, dim3(256), dim3(128), 0, stream, Wab, Win, WuT);
  hipLaunchKernelGGL(k_wcot, dim3(128), dim3(256), 0, stream, Wout, Wc, WallT);
  hipLaunchKernelGGL(k_wxt, dim3(128), dim3(128), 0, stream, WdO, Win, WallT);
  hipLaunchKernelGGL(k_wfold, dim3(256), dim3(256), 0, stream, Wab, wln, Wf);
  hipLaunchKernelGGL(k_bias, dim3(1), dim3(256), 0, stream,
                     Wout, WdO, Wab, bin, bab, bc, bd, bout, bu, ball);
  hipLaunchKernelGGL(k_ugemm, dim3(2048, 2), dim3(256), 0, stream, x, WuT, bu, u);
  hipLaunchKernelGGL(k_scan, dim3(NB), dim3(512), 0, stream, Wf, wln, u);
  hipLaunchKernelGGL(k_ogemm, dim3(2048), dim3(256), 0, stream, x, u, WallT, ball, out);
}

// Round 4
// 1821.180 us; speedup vs baseline: 3.3420x; 2.3334x over previous
//
#include <hip/hip_runtime.h>
#include <cstdint>

#define DIM 128
#define DSTATE 256
#define NB 64
#define NT 4096
#define NCHUNK 4
#define CHLEN (NT / NCHUNK)
#define WARM 192
#define REPS 1e-5f

typedef float4 f4;

__device__ __forceinline__ void fma4(f4& a, float s, const f4& w) {
  a.x = fmaf(s, w.x, a.x);
  a.y = fmaf(s, w.y, a.y);
  a.z = fmaf(s, w.z, a.z);
  a.w = fmaf(s, w.w, a.w);
}

// elementwise a += b*c
__device__ __forceinline__ void fma44(f4& a, const f4& b, const f4& c) {
  a.x = fmaf(b.x, c.x, a.x);
  a.y = fmaf(b.y, c.y, a.y);
  a.z = fmaf(b.z, c.z, a.z);
  a.w = fmaf(b.w, c.w, a.w);
}

__device__ __forceinline__ float hadd4(const f4& a) {
  return (a.x + a.y) + (a.z + a.w);
}

// cross-lane add via DPP quad_perm (VALU pipe, not DS): xor1 / xor2
__device__ __forceinline__ float dpp_xadd1(float x) {
  int v = __builtin_amdgcn_mov_dpp(__builtin_bit_cast(int, x), 0xB1, 0xF, 0xF, true);
  return x + __builtin_bit_cast(float, v);
}
__device__ __forceinline__ float dpp_xadd2(float x) {
  int v = __builtin_amdgcn_mov_dpp(__builtin_bit_cast(int, x), 0x4E, 0xF, 0xF, true);
  return x + __builtin_bit_cast(float, v);
}
// ds_swizzle xor-add (DS pipe), pattern = (xor<<10)|0x1F
#define SWZ_XADD(x, imm) \
  ((x) + __builtin_bit_cast(float, __builtin_amdgcn_ds_swizzle(__builtin_bit_cast(int, (x)), (imm))))

// ---------------- precompute: fused weight matrices ----------------
__global__ void k_wdo(const float* __restrict__ Wout, const float* __restrict__ Wd,
                      float* __restrict__ WdO) {
  int c = blockIdx.x, j = threadIdx.x;
  float s = 0.f;
  for (int k = 0; k < 128; ++k) s = fmaf(Wout[c * 128 + k], Wd[k * 128 + j], s);
  WdO[c * 128 + j] = s;
}

__global__ void k_wut(const float* __restrict__ Wab, const float* __restrict__ Win,
                      float* __restrict__ WuT) {
  int c = blockIdx.x;   // 256
  int k = threadIdx.x;  // 128
  float s = 0.f;
  for (int j = 0; j < 128; ++j) s = fmaf(Wab[c * 384 + 256 + j], Win[j * 128 + k], s);
  WuT[k * 256 + c] = s;
}

__global__ void k_wcot(const float* __restrict__ Wout, const float* __restrict__ Wc,
                       float* __restrict__ WallT) {
  int c = blockIdx.x;   // 128
  int k = threadIdx.x;  // 256
  float s = 0.f;
  for (int j = 0; j < 128; ++j) s = fmaf(Wout[c * 128 + j], Wc[j * 256 + k], s);
  WallT[(size_t)(128 + k) * 128 + c] = s;
}

__global__ void k_wxt(const float* __restrict__ WdO, const float* __restrict__ Win,
                      float* __restrict__ WallT) {
  int c = blockIdx.x;   // 128
  int k = threadIdx.x;  // 128
  float s = 0.f;
  for (int j = 0; j < 128; ++j) s = fmaf(WdO[c * 128 + j], Win[j * 128 + k], s);
  WallT[(size_t)k * 128 + c] = s;
}

// Wf[r][k] = Wab[r][k] * wln[k]
__global__ void k_wfold(const float* __restrict__ Wab, const float* __restrict__ wln,
                        float* __restrict__ Wf) {
  int r = blockIdx.x;
  int k = threadIdx.x;
  Wf[r * 256 + k] = Wab[r * 384 + k] * wln[k];
}

__global__ void k_bias(const float* __restrict__ Wout, const float* __restrict__ WdO,
                       const float* __restrict__ Wab, const float* __restrict__ bin,
                       const float* __restrict__ bab, const float* __restrict__ bc,
                       const float* __restrict__ bd, const float* __restrict__ bout,
                       float* __restrict__ bu, float* __restrict__ ball) {
  int t = threadIdx.x;  // 256
  if (t < 128) {
    float s = bout[t];
    for (int j = 0; j < 128; ++j) {
      s = fmaf(Wout[t * 128 + j], bc[j] + bd[j], s);
      s = fmaf(WdO[t * 128 + j], bin[j], s);
    }
    ball[t] = s;
  }
  float s2 = bab[t];
  for (int j = 0; j < 128; ++j) s2 = fmaf(Wab[t * 384 + 256 + j], bin[j], s2);
  bu[t] = s2;
}

// ---------------- u = x @ WuT + bu  ([B*T,128]@[128,256]) ----------------
__global__ __launch_bounds__(256, 2) void k_ugemm(const float* __restrict__ x,
                                                  const float* __restrict__ WuT,
                                                  const float* __restrict__ bu,
                                                  float* __restrict__ u) {
  __shared__ f4 xs[128 * 9];   // [row][36 floats] padded
  __shared__ f4 ws[32 * 32];   // [k][128 floats]
  const int tid = threadIdx.x;
  const int tc = tid & 15;
  const int trr = tid >> 4;
  const size_t row0 = (size_t)blockIdx.x * 128;
  const int cb = blockIdx.y * 128;

  f4 accA[8], accB[8];
  {
    f4 ba = *(const f4*)(bu + cb + tc * 4);
    f4 bb = *(const f4*)(bu + cb + 64 + tc * 4);
#pragma unroll
    for (int i = 0; i < 8; ++i) { accA[i] = ba; accB[i] = bb; }
  }

  for (int k0 = 0; k0 < DIM; k0 += 32) {
#pragma unroll
    for (int l = 0; l < 4; ++l) {
      int f = tid + l * 256;
      int rr = f >> 3, kq = f & 7;
      xs[rr * 9 + kq] = *(const f4*)(x + (row0 + rr) * DIM + k0 + kq * 4);
    }
#pragma unroll
    for (int l = 0; l < 4; ++l) {
      int f = tid + l * 256;
      int kk = f >> 5, cq = f & 31;
      ws[kk * 32 + cq] = *(const f4*)(WuT + (size_t)(k0 + kk) * DSTATE + cb + cq * 4);
    }
    __syncthreads();
#pragma unroll
    for (int g = 0; g < 8; ++g) {
      f4 xv[8];
#pragma unroll
      for (int i = 0; i < 8; ++i) xv[i] = xs[(trr + 16 * i) * 9 + g];
#pragma unroll
      for (int d = 0; d < 4; ++d) {
        f4 wa = ws[(g * 4 + d) * 32 + tc];
        f4 wb = ws[(g * 4 + d) * 32 + 16 + tc];
#pragma unroll
        for (int i = 0; i < 8; ++i) {
          float xm = (d == 0) ? xv[i].x : (d == 1) ? xv[i].y : (d == 2) ? xv[i].z : xv[i].w;
          fma4(accA[i], xm, wa);
          fma4(accB[i], xm, wb);
        }
      }
    }
    __syncthreads();
  }
#pragma unroll
  for (int i = 0; i < 8; ++i) {
    size_t r = row0 + trr + 16 * i;
    *(f4*)(u + r * DSTATE + cb + tc * 4) = accA[i];
    *(f4*)(u + r * DSTATE + cb + 64 + tc * 4) = accB[i];
  }
}

// ---------------- stage warmup windows of u into scratch (reuses d_out) ----------------
// boundary c in {0,1,2} serves chunk c+1: u[b][(c+1)*CHLEN - WARM + i], i in [0,WARM)
__global__ void k_uwarm(const float* __restrict__ u, float* __restrict__ uw) {
  int b = blockIdx.x / 3, c = blockIdx.x % 3;
  const f4* src = (const f4*)(u + ((size_t)b * NT + (size_t)(c + 1) * CHLEN - WARM) * DSTATE);
  f4* dst = (f4*)(uw + ((size_t)b * 3 + c) * ((size_t)WARM * DSTATE));
  for (int i = threadIdx.x; i < WARM * DSTATE / 4; i += 256) dst[i] = src[i];
}

// ---------------- sequential scan: 256 WGs (1/CU), chunk-parallel with warmup ----------
// Wave w owns rows w*32..w*32+31. lane = rb*8+kb: thread = 4 rows (r0=w*32+rb*4) x
// 32-float k-slice (kb*32..). LDS latent: 8 slices x (32+4 pad) floats -> 8 distinct
// broadcast addresses per ds_read_b128, conflict-free. Row reduce over kb: xor1/xor2
// via DPP (VALU), xor4 via ds_swizzle. One barrier/step; rmsnorm scale folded into
// next step via sprev (Wf = Wab*diag(wln)).
__global__ __launch_bounds__(512, 2) void k_scan(const float* __restrict__ Wf,
                                                 const float* __restrict__ wlng,
                                                 float* __restrict__ u,
                                                 const float* __restrict__ uw) {
  __shared__ float lat[2][8 * 36];
  __shared__ f4 partv[2][2];
  const int tid = threadIdx.x;
  const int w = tid >> 6;
  const int lane = tid & 63;
  const int rb = lane >> 3;
  const int kb = lane & 7;
  const int r0 = w * 32 + rb * 4;
  const int b = blockIdx.x & 63;
  const int c = blockIdx.x >> 6;               // 0..3
  const int emit0 = c * CHLEN;
  const int tstart = emit0 - (c ? WARM : 0);
  const int tend = emit0 + CHLEN;

  float* ub = u + (size_t)b * ((size_t)NT * DSTATE);
  // uwb + t*DSTATE == warmup copy of u[b][t] for t in [emit0-WARM, emit0)
  const float* uwb =
      c ? (uw + ((size_t)b * 3 + (c - 1)) * ((size_t)WARM * DSTATE) -
           (size_t)(emit0 - WARM) * DSTATE)
        : (const float*)ub;

  // weights: 4 rows x 32 floats in VGPRs (128 regs)
  f4 W0[8], W1[8], W2[8], W3[8];
  {
    const f4* pw = (const f4*)(Wf + (size_t)r0 * 256 + kb * 32);
#pragma unroll
    for (int q = 0; q < 8; ++q) {
      W0[q] = pw[q]; W1[q] = pw[64 + q]; W2[q] = pw[128 + q]; W3[q] = pw[192 + q];
    }
  }
  const f4 wlnv = *(const f4*)(wlng + r0);

  if (tid < 288) { lat[0][tid] = 0.f; lat[1][tid] = 0.f; }
  __syncthreads();

  const f4* rd0 = (const f4*)(lat[0] + kb * 36);
  const f4* rd1 = (const f4*)(lat[1] + kb * 36);
  float* wr0 = lat[0] + w * 36 + rb * 4;
  float* wr1 = lat[1] + w * 36 + rb * 4;

  float sprev = 1.0f;

#define UAT(T_) ((((T_) < emit0) ? uwb : (const float*)ub) + (size_t)(T_)*DSTATE + r0)

  f4 uA = *(const f4*)UAT(tstart);
  f4 uB = *(const f4*)UAT(tstart + 1);

#define SCAN_STEP(RD, WR, PP, UV, TT, EM)                                      \
  {                                                                            \
    f4 a0 = {0, 0, 0, 0}, a1 = {0, 0, 0, 0}, a2 = {0, 0, 0, 0},                \
       a3 = {0, 0, 0, 0};                                                      \
    _Pragma("unroll")                                                          \
    for (int q = 0; q < 8; ++q) {                                              \
      f4 lv = RD[q];                                                           \
      fma44(a0, W0[q], lv); fma44(a1, W1[q], lv);                              \
      fma44(a2, W2[q], lv); fma44(a3, W3[q], lv);                              \
    }                                                                          \
    float d0 = hadd4(a0), d1 = hadd4(a1), d2 = hadd4(a2), d3 = hadd4(a3);      \
    d0 = dpp_xadd1(d0); d1 = dpp_xadd1(d1); d2 = dpp_xadd1(d2);                \
    d3 = dpp_xadd1(d3);                                                        \
    d0 = dpp_xadd2(d0); d1 = dpp_xadd2(d1); d2 = dpp_xadd2(d2);                \
    d3 = dpp_xadd2(d3);                                                        \
    d0 = SWZ_XADD(d0, 0x101F); d1 = SWZ_XADD(d1, 0x101F);                      \
    d2 = SWZ_XADD(d2, 0x101F); d3 = SWZ_XADD(d3, 0x101F);                      \
    float pre0 = fmaf(d0, sprev, (UV).x);                                      \
    float pre1 = fmaf(d1, sprev, (UV).y);                                      \
    float pre2 = fmaf(d2, sprev, (UV).z);                                      \
    float pre3 = fmaf(d3, sprev, (UV).w);                                      \
    if (kb == 0) *(f4*)(WR) = make_float4(pre0, pre1, pre2, pre3);             \
    float ss = fmaf(pre0, pre0, fmaf(pre1, pre1, fmaf(pre2, pre2,              \
               pre3 * pre3)));                                                 \
    ss = SWZ_XADD(ss, 0x201F);                                                 \
    ss = SWZ_XADD(ss, 0x401F);                                                 \
    ss += __shfl_xor(ss, 32);                                                  \
    if (lane == 0) ((float*)&partv[PP][0])[w] = ss;                            \
    __syncthreads();                                                           \
    f4 p0 = partv[PP][0], p1 = partv[PP][1];                                   \
    float tot = hadd4(p0) + hadd4(p1);                                         \
    float s = rsqrtf(tot * (1.0f / 256.0f) + REPS);                            \
    if ((EM) && kb == 0) {                                                     \
      *(f4*)&ub[(size_t)(TT)*DSTATE + r0] =                                    \
          make_float4(pre0 * s * wlnv.x, pre1 * s * wlnv.y,                    \
                      pre2 * s * wlnv.z, pre3 * s * wlnv.w);                   \
    }                                                                          \
    sprev = s;                                                                 \
  }

  for (int t = tstart; t < tend; t += 2) {
    f4 pfA = {0, 0, 0, 0}, pfB = {0, 0, 0, 0};
    if (t + 2 < tend) {
      pfA = *(const f4*)UAT(t + 2);
      pfB = *(const f4*)UAT(t + 3);
    }
    const bool em = (t >= emit0);   // WARM is even: pair shares emit status
    SCAN_STEP(rd0, wr1, 0, uA, t, em)
    SCAN_STEP(rd1, wr0, 1, uB, t + 1, em)
    uA = pfA; uB = pfB;
  }
#undef SCAN_STEP
#undef UAT
}

// ---------------- out = [x,h] @ WallT + ball  ([B*T,384]@[384,128]) ----------------
__global__ __launch_bounds__(256, 2) void k_ogemm(const float* __restrict__ x,
                                                  const float* __restrict__ h,
                                                  const float* __restrict__ WallT,
                                                  const float* __restrict__ ball,
                                                  float* __restrict__ out) {
  __shared__ f4 xs[128 * 9];
  __shared__ f4 ws[32 * 32];
  const int tid = threadIdx.x;
  const int tc = tid & 15;
  const int trr = tid >> 4;
  const size_t row0 = (size_t)blockIdx.x * 128;

  f4 accA[8], accB[8];
  {
    f4 ba = *(const f4*)(ball + tc * 4);
    f4 bb = *(const f4*)(ball + 64 + tc * 4);
#pragma unroll
    for (int i = 0; i < 8; ++i) { accA[i] = ba; accB[i] = bb; }
  }

  for (int ch = 0; ch < 12; ++ch) {
    const int k0 = ch * 32;
    const float* src = (k0 < DIM) ? x : h;
    const int rstride = (k0 < DIM) ? DIM : DSTATE;
    const int koff = (k0 < DIM) ? k0 : (k0 - DIM);
#pragma unroll
    for (int l = 0; l < 4; ++l) {
      int f = tid + l * 256;
      int rr = f >> 3, kq = f & 7;
      xs[rr * 9 + kq] = *(const f4*)(src + (row0 + rr) * rstride + koff + kq * 4);
    }
#pragma unroll
    for (int l = 0; l < 4; ++l) {
      int f = tid + l * 256;
      int kk = f >> 5, cq = f & 31;
      ws[kk * 32 + cq] = *(const f4*)(WallT + (size_t)(k0 + kk) * DIM + cq * 4);
    }
    __syncthreads();
#pragma unroll
    for (int g = 0; g < 8; ++g) {
      f4 xv[8];
#pragma unroll
      for (int i = 0; i < 8; ++i) xv[i] = xs[(trr + 16 * i) * 9 + g];
#pragma unroll
      for (int d = 0; d < 4; ++d) {
        f4 wa = ws[(g * 4 + d) * 32 + tc];
        f4 wb = ws[(g * 4 + d) * 32 + 16 + tc];
#pragma unroll
        for (int i = 0; i < 8; ++i) {
          float xm = (d == 0) ? xv[i].x : (d == 1) ? xv[i].y : (d == 2) ? xv[i].z : xv[i].w;
          fma4(accA[i], xm, wa);
          fma4(accB[i], xm, wb);
        }
      }
    }
    __syncthreads();
  }
#pragma unroll
  for (int i = 0; i < 8; ++i) {
    size_t r = row0 + trr + 16 * i;
    *(f4*)(out + r * DIM + tc * 4) = accA[i];
    *(f4*)(out + r * DIM + 64 + tc * 4) = accB[i];
  }
}

extern "C" void kernel_launch(void* const* d_in, const int* in_sizes, int n_in,
                              void* d_out, int out_size, void* d_ws, size_t ws_size,
                              hipStream_t stream) {
  const float* x    = (const float*)d_in[0];
  const float* Win  = (const float*)d_in[1];
  const float* bin  = (const float*)d_in[2];
  const float* Wab  = (const float*)d_in[3];
  const float* bab  = (const float*)d_in[4];
  const float* wln  = (const float*)d_in[5];
  const float* Wc   = (const float*)d_in[6];
  const float* bc   = (const float*)d_in[7];
  const float* Wd   = (const float*)d_in[8];
  const float* bd   = (const float*)d_in[9];
  const float* Wout = (const float*)d_in[10];
  const float* bout = (const float*)d_in[11];
  float* out = (float*)d_out;
  float* wsf = (float*)d_ws;

  float* u     = wsf;                                   // 64*4096*256 floats (u -> h in place)
  float* WuT   = u + (size_t)NB * NT * DSTATE;          // 128*256
  float* WallT = WuT + (size_t)DIM * DSTATE;            // 384*128
  float* WdO   = WallT + (size_t)384 * DIM;             // 128*128
  float* Wf    = WdO + (size_t)DIM * DIM;               // 256*256
  float* bu    = Wf + (size_t)DSTATE * DSTATE;          // 256
  float* ball  = bu + DSTATE;                           // 128
  // warmup staging reuses d_out (dead until k_ogemm fully overwrites it):
  float* uwarm = out;                                   // 64*3*192*256 floats <= out_size

  hipLaunchKernelGGL(k_wdo, dim3(128), dim3(128), 0, stream, Wout, Wd, WdO);
  hipLaunchKernelGGL(k_wut, dim3(256), dim3(128), 0, stream, Wab, Win, WuT);
  hipLaunchKernelGGL(k_wcot, dim3(128), dim3(256), 0, stream, Wout, Wc, WallT);
  hipLaunchKernelGGL(k_wxt, dim3(128), dim3(128), 0, stream, WdO, Win, WallT);
  hipLaunchKernelGGL(k_wfold, dim3(256), dim3(256), 0, stream, Wab, wln, Wf);
  hipLaunchKernelGGL(k_bias, dim3(1), dim3(256), 0, stream,
                     Wout, WdO, Wab, bin, bab, bc, bd, bout, bu, ball);
  hipLaunchKernelGGL(k_ugemm, dim3(2048, 2), dim3(256), 0, stream, x, WuT, bu, u);
  hipLaunchKernelGGL(k_uwarm, dim3(NB * 3), dim3(256), 0, stream, u, uwarm);
  hipLaunchKernelGGL(k_scan, dim3(NB * NCHUNK), dim3(512), 0, stream, Wf, wln, u, uwarm);
  hipLaunchKernelGGL(k_ogemm, dim3(2048), dim3(256), 0, stream, x, u, WallT, ball, out);
}